// Round 2
// baseline (269.211 us; speedup 1.0000x reference)
//
#include <hip/hip_runtime.h>
#include <hip/hip_cooperative_groups.h>
#include <cstdint>
#include <cstring>

namespace cg = cooperative_groups;

// ---------------------------------------------------------------------------
// LinearBNNoise, single cooperative kernel (R2).
// Grid 256 blocks x 512 thr = 1 block/CU, each block owns 256 rows.
// h1 (256x48) and h2 (256x24) tiles stay in LDS across grid.sync()s:
// eliminates the 37.8 MB h1/h2 HBM round-trips + 3 launch gaps of the
// 4-dispatch version (78 us). Phases:
//   P0 w1->bf16 (global wb1) + zero stats     | grid.sync
//   P1 MFMA bf16 GEMM1 -> h1s LDS + stats1    | grid.sync
//   P2 BN1+noise+ReLU (in-place) -> GEMM2 -> h2s LDS + stats2 | grid.sync
//   P3 BN2+noise+ReLU -> GEMM3 -> coalesced out
// Stats via 8-replica device-scope atomics; replica reads/zeroing use
// __hip_atomic_* (agent scope) for cross-XCD coherence; __threadfence()
// before each grid.sync releases plain stores (wb1).
// ---------------------------------------------------------------------------

constexpr int MROWS = 65536;
constexpr int KDIM  = 784;
constexpr int KPAD  = 800;   // 25 * 32, zero-padded bf16 weights
constexpr int F1 = 48, F2 = 24, F3 = 10;
constexpr int NBLK = 256;
constexpr int NTHR = 512;    // 8 waves
constexpr int RPB  = 256;    // rows per block

using frag_ab = __attribute__((ext_vector_type(8))) short;  // 8 bf16 (4 VGPRs)
using frag_cd = __attribute__((ext_vector_type(4))) float;  // 4 fp32

union UB { uint4 u; frag_ab f; };

// ---------------- threefry2x32 (20 rounds) ----------------
__device__ __forceinline__ uint32_t rotl32(uint32_t v, int r) {
  return (v << r) | (v >> (32 - r));
}

// XOR of both output words of threefry2x32(key=(k0,k1), counts=(0, ctr))
__device__ __forceinline__ uint32_t tf_mix(uint32_t k0, uint32_t k1, uint32_t ctr) {
  uint32_t ks2 = k0 ^ k1 ^ 0x1BD11BDAu;
  uint32_t x0 = k0;
  uint32_t x1 = ctr + k1;
#define TFR(r) { x0 += x1; x1 = rotl32(x1, r); x1 ^= x0; }
  TFR(13) TFR(15) TFR(26) TFR(6)
  x0 += k1;  x1 += ks2 + 1u;
  TFR(17) TFR(29) TFR(16) TFR(24)
  x0 += ks2; x1 += k0 + 2u;
  TFR(13) TFR(15) TFR(26) TFR(6)
  x0 += k0;  x1 += k1 + 3u;
  TFR(17) TFR(29) TFR(16) TFR(24)
  x0 += k1;  x1 += ks2 + 4u;
  TFR(13) TFR(15) TFR(26) TFR(6)
  x0 += ks2; x1 += k0 + 5u;
#undef TFR
  return x0 ^ x1;
}

// XLA ErfInv f32 (Giles). Fast log: |u| <= 1-2^-23 so 1-u*u >= ~2^-22;
// -__logf(1-u*u) matches log1pf(-u*u) to ~1e-6 in w.
__device__ __forceinline__ float erfinv_f32(float x) {
  float t = fmaxf(1.0f - x * x, 1.0e-30f);
  float w = -__logf(t);
  float p;
  if (w < 5.0f) {
    w = w - 2.5f;
    p = 2.81022636e-08f;
    p = fmaf(p, w, 3.43273939e-07f);
    p = fmaf(p, w, -3.5233877e-06f);
    p = fmaf(p, w, -4.39150654e-06f);
    p = fmaf(p, w, 0.00021858087f);
    p = fmaf(p, w, -0.00125372503f);
    p = fmaf(p, w, -0.00417768164f);
    p = fmaf(p, w, 0.246640727f);
    p = fmaf(p, w, 1.50140941f);
  } else {
    w = sqrtf(w) - 3.0f;
    p = -0.000200214257f;
    p = fmaf(p, w, 0.000100950558f);
    p = fmaf(p, w, 0.00134934322f);
    p = fmaf(p, w, -0.00367342844f);
    p = fmaf(p, w, 0.00573950773f);
    p = fmaf(p, w, -0.0076224613f);
    p = fmaf(p, w, 0.00943887047f);
    p = fmaf(p, w, 1.00167406f);
    p = fmaf(p, w, 2.83297682f);
  }
  return p * x;
}

__device__ __forceinline__ float noise_normal(uint32_t k0, uint32_t k1, uint32_t ctr) {
  uint32_t bits = tf_mix(k0, k1, ctr);
  float f = __uint_as_float((bits >> 9) | 0x3f800000u) - 1.0f; // [0,1)
  const float lo = -0.99999994f;
  float u = fmaxf(lo, f * 2.0f + lo);
  return 1.41421356f * erfinv_f32(u);
}

// hardware packed f32->bf16 (RNE), low word = a. gfx950 has no builtin.
__device__ __forceinline__ uint32_t cvtpk(float a, float b) {
  uint32_t r;
  asm("v_cvt_pk_bf16_f32 %0, %1, %2" : "=v"(r) : "v"(a), "v"(b));
  return r;
}

// agent-scope coherent accesses for the cross-XCD stats block
__device__ __forceinline__ float ald(const float* p) {
  return __hip_atomic_load(p, __ATOMIC_RELAXED, __HIP_MEMORY_SCOPE_AGENT);
}
__device__ __forceinline__ void ast(float* p, float v) {
  __hip_atomic_store(p, v, __ATOMIC_RELAXED, __HIP_MEMORY_SCOPE_AGENT);
}

// st layout (floats): fsum1[8][48]@0  fssq1[8][48]@384
//                     fsum2[8][24]@768 fssq2[8][24]@960   (2048 total)
__global__ __launch_bounds__(NTHR, 2) void k_fused(
    const float* __restrict__ x, const float* __restrict__ w1,
    const float* __restrict__ b1, const float* __restrict__ gamma1,
    const float* __restrict__ beta1, const float* __restrict__ w2,
    const float* __restrict__ b2, const float* __restrict__ gamma2,
    const float* __restrict__ beta2, const float* __restrict__ w3,
    const float* __restrict__ b3, float* __restrict__ out,
    ushort* __restrict__ wb1, float* __restrict__ st,
    float u1, float u2, uint32_t kn1a, uint32_t kn1b,
    uint32_t kn2a, uint32_t kn2b) {
  __shared__ float h1s[RPB][49];       // 50.2 KB  h1 then a1 (in place)
  __shared__ float h2s[RPB][25];       // 25.6 KB
  __shared__ float a2s[RPB][25];       // 25.6 KB
  __shared__ float w2s[48][25];        // w2s[k][c]
  __shared__ float w3s[24][10];        // w3s[k][c]
  __shared__ float reds[8][48], redq[8][48];
  __shared__ float bnp[4][48];
  __shared__ float outs[RPB * F3];     // 10.2 KB
  __shared__ float scal[2];

  const int t = threadIdx.x;
  const int rowbase = blockIdx.x * RPB;
  cg::grid_group grid = cg::this_grid();

  // ---------------- P0: prep wb1 (bf16 RNE, zero-padded) + zero stats ------
  {
    int gid = blockIdx.x * NTHR + t;
    if (gid < 2048) ast(&st[gid], 0.f);
    if (gid < F1 * KPAD) {
      int n = gid / KPAD, k = gid - n * KPAD;
      float v = (k < KDIM) ? w1[n * KDIM + k] : 0.f;
      uint32_t u = __float_as_uint(v);
      u += 0x7fffu + ((u >> 16) & 1u);
      wb1[gid] = (ushort)(u >> 16);
    }
  }
  __threadfence();
  grid.sync();

  // ---------------- P1: MFMA bf16 GEMM1 -> h1s (LDS) + stats1 --------------
  {
    const int w = t >> 6, l = t & 63;
    const int lane16 = l & 15, quad = l >> 4;
    frag_cd acc[2][3];
#pragma unroll
    for (int g = 0; g < 2; ++g)
#pragma unroll
      for (int ct = 0; ct < 3; ++ct)
#pragma unroll
        for (int r = 0; r < 4; ++r) acc[g][ct][r] = 0.f;

    // wave w: rows w*32 .. w*32+31 (two 16-row groups), all 48 cols
    const float* ap0 = x + (size_t)(rowbase + w * 32 + lane16) * KDIM + quad * 8;
    const float* ap1 = ap0 + (size_t)16 * KDIM;
    const ushort* bp0 = wb1 + (size_t)lane16 * KPAD + quad * 8;
    const ushort* bp1 = bp0 + 16 * KPAD;
    const ushort* bp2 = bp0 + 32 * KPAD;

    float4 a00 = *(const float4*)(ap0);
    float4 a01 = *(const float4*)(ap0 + 4);
    float4 a10 = *(const float4*)(ap1);
    float4 a11 = *(const float4*)(ap1 + 4);
    uint4 cb0 = *(const uint4*)(bp0);
    uint4 cb1 = *(const uint4*)(bp1);
    uint4 cb2 = *(const uint4*)(bp2);

    for (int s = 0; s < 25; ++s) {
      float4 n00 = make_float4(0.f, 0.f, 0.f, 0.f), n01 = n00, n10 = n00, n11 = n00;
      uint4 nb0 = make_uint4(0, 0, 0, 0), nb1 = nb0, nb2 = nb0;
      if (s < 24) {
        const int ko = (s + 1) * 32;
        if (ko + quad * 8 + 8 <= KDIM) {   // tail: s=23 quads 2..3 stay zero
          n00 = *(const float4*)(ap0 + ko);
          n01 = *(const float4*)(ap0 + ko + 4);
          n10 = *(const float4*)(ap1 + ko);
          n11 = *(const float4*)(ap1 + ko + 4);
        }
        nb0 = *(const uint4*)(bp0 + ko);   // wb1 zero-padded to 800
        nb1 = *(const uint4*)(bp1 + ko);
        nb2 = *(const uint4*)(bp2 + ko);
      }
      UB A0, A1;
      A0.u.x = cvtpk(a00.x, a00.y);
      A0.u.y = cvtpk(a00.z, a00.w);
      A0.u.z = cvtpk(a01.x, a01.y);
      A0.u.w = cvtpk(a01.z, a01.w);
      A1.u.x = cvtpk(a10.x, a10.y);
      A1.u.y = cvtpk(a10.z, a10.w);
      A1.u.z = cvtpk(a11.x, a11.y);
      A1.u.w = cvtpk(a11.z, a11.w);
      UB B;
      B.u = cb0;
      acc[0][0] = __builtin_amdgcn_mfma_f32_16x16x32_bf16(A0.f, B.f, acc[0][0], 0, 0, 0);
      acc[1][0] = __builtin_amdgcn_mfma_f32_16x16x32_bf16(A1.f, B.f, acc[1][0], 0, 0, 0);
      B.u = cb1;
      acc[0][1] = __builtin_amdgcn_mfma_f32_16x16x32_bf16(A0.f, B.f, acc[0][1], 0, 0, 0);
      acc[1][1] = __builtin_amdgcn_mfma_f32_16x16x32_bf16(A1.f, B.f, acc[1][1], 0, 0, 0);
      B.u = cb2;
      acc[0][2] = __builtin_amdgcn_mfma_f32_16x16x32_bf16(A0.f, B.f, acc[0][2], 0, 0, 0);
      acc[1][2] = __builtin_amdgcn_mfma_f32_16x16x32_bf16(A1.f, B.f, acc[1][2], 0, 0, 0);
      a00 = n00; a01 = n01; a10 = n10; a11 = n11;
      cb0 = nb0; cb1 = nb1; cb2 = nb2;
    }

    // epilogue: bias, h1 -> LDS, per-feature partial stats
    float bias[3];
#pragma unroll
    for (int ct = 0; ct < 3; ++ct) bias[ct] = b1[ct * 16 + lane16];
    float psum[3] = {0.f, 0.f, 0.f}, pssq[3] = {0.f, 0.f, 0.f};
#pragma unroll
    for (int g = 0; g < 2; ++g)
#pragma unroll
      for (int r = 0; r < 4; ++r) {
        const int lrow = w * 32 + g * 16 + quad * 4 + r;   // C row = quad*4+reg
#pragma unroll
        for (int ct = 0; ct < 3; ++ct) {
          float v = acc[g][ct][r] + bias[ct];
          h1s[lrow][ct * 16 + lane16] = v;                 // C col = lane16
          psum[ct] += v;
          pssq[ct] += v * v;
        }
      }
#pragma unroll
    for (int ct = 0; ct < 3; ++ct) {
      psum[ct] += __shfl_xor(psum[ct], 16, 64);
      psum[ct] += __shfl_xor(psum[ct], 32, 64);
      pssq[ct] += __shfl_xor(pssq[ct], 16, 64);
      pssq[ct] += __shfl_xor(pssq[ct], 32, 64);
    }
    if (quad == 0) {
#pragma unroll
      for (int ct = 0; ct < 3; ++ct) {
        reds[w][ct * 16 + lane16] = psum[ct];
        redq[w][ct * 16 + lane16] = pssq[ct];
      }
    }
  }
  __syncthreads();
  if (t < F1) {
    float s = 0.f, q = 0.f;
#pragma unroll
    for (int w = 0; w < 8; ++w) { s += reds[w][t]; q += redq[w][t]; }
    const int rep = blockIdx.x & 7;
    atomicAdd(&st[rep * 48 + t], s);
    atomicAdd(&st[384 + rep * 48 + t], q);
  }
  __threadfence();
  grid.sync();

  // ---------------- P2: BN1 finalize + noise + ReLU -> GEMM2 -> h2s --------
  {
    float cm = 0.f, cs = 0.f;
    if (t < F1) {
      float s0 = 0.f, q0 = 0.f;
#pragma unroll
      for (int rp = 0; rp < 8; ++rp) {
        s0 += ald(&st[rp * 48 + t]);
        q0 += ald(&st[384 + rp * 48 + t]);
      }
      float m = s0 * (1.f / 65536.f);
      float v = q0 * (1.f / 65536.f) - m * m;
      float r = rsqrtf(v + 1e-5f);
      float g = gamma1[t], b = beta1[t];
      bnp[0][t] = m; bnp[1][t] = r; bnp[2][t] = g; bnp[3][t] = b;
      cm = b;
      cs = g * g * r * r * v + b * b;
    }
    if (t < 64) {
#pragma unroll
      for (int off = 32; off > 0; off >>= 1) {
        cm += __shfl_down(cm, off, 64);
        cs += __shfl_down(cs, off, 64);
      }
      if (t == 0) {
        float m = cm / (float)F1;
        float SS = 65536.f * cs;
        float Ntot = 65536.f * (float)F1;
        float s2 = (SS - Ntot * m * m) / (Ntot - 1.f);  // ddof=1
        scal[0] = m;
        scal[1] = sqrtf(s2) * u1;
      }
    }
    for (int e = t; e < F2 * 48; e += NTHR) {
      int c = e / 48, k = e - c * 48;
      w2s[k][c] = w2[e];
    }
  }
  __syncthreads();
  {
    const float m1 = scal[0], su1 = scal[1];
#pragma unroll
    for (int p = 0; p < 2; ++p) {
      const int rr = p * 128 + (t >> 2);
      const int cc0 = (t & 3) * 12;
      const int grow = rowbase + rr;
      const uint32_t cbase = (uint32_t)grow * 48u + (uint32_t)cc0;
#pragma unroll
      for (int j = 0; j < 12; ++j) {
        int c = cc0 + j;
        float v = h1s[rr][c];
        float bn = (v - bnp[0][c]) * bnp[1][c] * bnp[2][c] + bnp[3][c];
        float nz = noise_normal(kn1a, kn1b, cbase + (uint32_t)j);
        float val = bn + fmaf(su1, nz, m1);
        h1s[rr][c] = fmaxf(val, 0.f);   // a1 in place
      }
    }
  }
  __syncthreads();
  {
    const int c0 = (t >> 7) * 6;
    float bb[6];
#pragma unroll
    for (int j = 0; j < 6; ++j) bb[j] = b2[c0 + j];
#pragma unroll
    for (int p = 0; p < 2; ++p) {
      const int row = p * 128 + (t & 127);
      float acc2[6] = {0.f, 0.f, 0.f, 0.f, 0.f, 0.f};
#pragma unroll
      for (int k = 0; k < 48; ++k) {
        float a = h1s[row][k];
#pragma unroll
        for (int j = 0; j < 6; ++j) acc2[j] = fmaf(a, w2s[k][c0 + j], acc2[j]);
      }
#pragma unroll
      for (int j = 0; j < 6; ++j) h2s[row][c0 + j] = acc2[j] + bb[j];
    }
  }
  __syncthreads();
  if (t < 192) {
    const int c = t % 24, ch = t / 24;
    float s = 0.f, q = 0.f;
#pragma unroll 8
    for (int r = ch * 32; r < ch * 32 + 32; ++r) {
      float v = h2s[r][c];
      s += v; q += v * v;
    }
    reds[ch][c] = s; redq[ch][c] = q;
  }
  __syncthreads();
  if (t < F2) {
    float s = 0.f, q = 0.f;
#pragma unroll
    for (int ch = 0; ch < 8; ++ch) { s += reds[ch][t]; q += redq[ch][t]; }
    const int rep = blockIdx.x & 7;
    atomicAdd(&st[768 + rep * 24 + t], s);
    atomicAdd(&st[960 + rep * 24 + t], q);
  }
  __threadfence();
  grid.sync();

  // ---------------- P3: BN2 finalize + noise + ReLU -> GEMM3 -> out --------
  {
    float cm = 0.f, cs = 0.f;
    if (t < F2) {
      float s0 = 0.f, q0 = 0.f;
#pragma unroll
      for (int rp = 0; rp < 8; ++rp) {
        s0 += ald(&st[768 + rp * 24 + t]);
        q0 += ald(&st[960 + rp * 24 + t]);
      }
      float m = s0 * (1.f / 65536.f);
      float v = q0 * (1.f / 65536.f) - m * m;
      float r = rsqrtf(v + 1e-5f);
      float g = gamma2[t], b = beta2[t];
      bnp[0][t] = m; bnp[1][t] = r; bnp[2][t] = g; bnp[3][t] = b;
      cm = b;
      cs = g * g * r * r * v + b * b;
    }
    if (t < 64) {
#pragma unroll
      for (int off = 32; off > 0; off >>= 1) {
        cm += __shfl_down(cm, off, 64);
        cs += __shfl_down(cs, off, 64);
      }
      if (t == 0) {
        float m = cm / (float)F2;
        float SS = 65536.f * cs;
        float Ntot = 65536.f * (float)F2;
        float s2 = (SS - Ntot * m * m) / (Ntot - 1.f);  // ddof=1
        scal[0] = m;
        scal[1] = sqrtf(s2) * u2;
      }
    }
    if (t < F3 * F2) {
      int c = t / 24, k = t - c * 24;
      w3s[k][c] = w3[t];
    }
  }
  __syncthreads();
  {
    const float m2 = scal[0], su2 = scal[1];
    for (int e = t; e < RPB * F2; e += NTHR) {
      int r = e / 24, c = e - r * 24;
      float v = h2s[r][c];
      float bn = (v - bnp[0][c]) * bnp[1][c] * bnp[2][c] + bnp[3][c];
      uint32_t ctr = (uint32_t)rowbase * 24u + (uint32_t)e;
      float nz = noise_normal(kn2a, kn2b, ctr);
      float val = bn + fmaf(su2, nz, m2);
      a2s[r][c] = fmaxf(val, 0.f);
    }
  }
  __syncthreads();
  {
    const int rr = t & 255;
    const int c0 = (t >> 8) * 5;
    float bb3[5];
#pragma unroll
    for (int j = 0; j < 5; ++j) bb3[j] = b3[c0 + j];
    float acc3[5] = {0.f, 0.f, 0.f, 0.f, 0.f};
#pragma unroll
    for (int k = 0; k < 24; ++k) {
      float a = a2s[rr][k];
#pragma unroll
      for (int j = 0; j < 5; ++j) acc3[j] = fmaf(a, w3s[k][c0 + j], acc3[j]);
    }
#pragma unroll
    for (int j = 0; j < 5; ++j) outs[rr * F3 + c0 + j] = acc3[j] + bb3[j];
  }
  __syncthreads();
  for (int e = t; e < RPB * F3; e += NTHR)
    out[(size_t)rowbase * F3 + e] = outs[e];
}

// ---------------- host threefry ----------------
static void host_tf(uint32_t k0, uint32_t k1, uint32_t c0, uint32_t c1,
                    uint32_t& o0, uint32_t& o1) {
  uint32_t ks2 = k0 ^ k1 ^ 0x1BD11BDAu;
  uint32_t x0 = c0 + k0, x1 = c1 + k1;
  auto R = [&](int r) { x0 += x1; x1 = (x1 << r) | (x1 >> (32 - r)); x1 ^= x0; };
  R(13); R(15); R(26); R(6);  x0 += k1;  x1 += ks2 + 1u;
  R(17); R(29); R(16); R(24); x0 += ks2; x1 += k0 + 2u;
  R(13); R(15); R(26); R(6);  x0 += k0;  x1 += k1 + 3u;
  R(17); R(29); R(16); R(24); x0 += k1;  x1 += ks2 + 4u;
  R(13); R(15); R(26); R(6);  x0 += ks2; x1 += k0 + 5u;
  o0 = x0; o1 = x1;
}

static float host_uniform12(uint32_t seed) {
  uint32_t ka, kb, t0, t1;
  host_tf(0u, seed, 0u, 0u, ka, kb);     // foldlike split, ctr 0 -> ku
  host_tf(ka, kb, 0u, 0u, t0, t1);       // random_bits of shape ()
  uint32_t bits = t0 ^ t1;               // partitionable: XOR of both words
  uint32_t fb = (bits >> 9) | 0x3f800000u;
  float f;
  std::memcpy(&f, &fb, 4);
  return f;
}

extern "C" void kernel_launch(void* const* d_in, const int* in_sizes, int n_in,
                              void* d_out, int out_size, void* d_ws, size_t ws_size,
                              hipStream_t stream) {
  (void)in_sizes; (void)n_in; (void)out_size; (void)ws_size;
  const float* x      = (const float*)d_in[0];
  const float* w1     = (const float*)d_in[1];
  const float* b1     = (const float*)d_in[2];
  const float* gamma1 = (const float*)d_in[3];
  const float* beta1  = (const float*)d_in[4];
  const float* w2     = (const float*)d_in[5];
  const float* b2     = (const float*)d_in[6];
  const float* gamma2 = (const float*)d_in[7];
  const float* beta2  = (const float*)d_in[8];
  const float* w3     = (const float*)d_in[9];
  const float* b3     = (const float*)d_in[10];
  float* out = (float*)d_out;

  float* st = (float*)d_ws;                       // 2048 floats
  ushort* wb1 = (ushort*)(st + 2048);             // 48*800 bf16

  uint32_t kn1a, kn1b, kn2a, kn2b;
  host_tf(0u, 1234u, 0u, 1u, kn1a, kn1b);         // kn of foldlike split(key(1234))
  host_tf(0u, 5678u, 0u, 1u, kn2a, kn2b);         // kn of foldlike split(key(5678))
  float u1 = host_uniform12(1234u);
  float u2 = host_uniform12(5678u);

  void* args[] = {
    (void*)&x, (void*)&w1, (void*)&b1, (void*)&gamma1, (void*)&beta1,
    (void*)&w2, (void*)&b2, (void*)&gamma2, (void*)&beta2,
    (void*)&w3, (void*)&b3, (void*)&out, (void*)&wb1, (void*)&st,
    (void*)&u1, (void*)&u2,
    (void*)&kn1a, (void*)&kn1b, (void*)&kn2a, (void*)&kn2b};
  hipLaunchCooperativeKernel(reinterpret_cast<void*>(k_fused),
                             dim3(NBLK), dim3(NTHR), args, 0, stream);
}

// Round 3
// 78.252 us; speedup vs baseline: 3.4403x; 3.4403x over previous
//
#include <hip/hip_runtime.h>
#include <cstdint>
#include <cstring>

// ---------------------------------------------------------------------------
// LinearBNNoise: x[65536,784] -> Linear(784,48) -> BN -> +noise(key 1234) -> ReLU
//                -> Linear(48,24) -> BN -> +noise(key 5678) -> ReLU -> Linear(24,10)
// R3: revert to the 4-dispatch R1 structure (78 us; R2's cooperative fusion
// collapsed memory concurrency to 320 GB/s and is abandoned). Single change:
// gemm1 K-loop unrolled 2x with depth-2 register prefetch (A and B for step
// s+2 in flight while consuming step s) to cover ~900cy HBM latency; hot loop
// (s<22) has no masks, tail split out. Everything else identical to R1.
// ---------------------------------------------------------------------------

constexpr int MROWS = 65536;
constexpr int KDIM  = 784;
constexpr int KPAD  = 800;   // 25 * 32, zero-padded bf16 weights
constexpr int F1 = 48, F2 = 24, F3 = 10;

using frag_ab = __attribute__((ext_vector_type(8))) short;  // 8 bf16 (4 VGPRs)
using frag_cd = __attribute__((ext_vector_type(4))) float;  // 4 fp32

union UB { uint4 u; frag_ab f; };

// ---------------- threefry2x32 (20 rounds) ----------------
__device__ __forceinline__ uint32_t rotl32(uint32_t v, int r) {
  return (v << r) | (v >> (32 - r));
}

// XOR of both output words of threefry2x32(key=(k0,k1), counts=(0, ctr))
__device__ __forceinline__ uint32_t tf_mix(uint32_t k0, uint32_t k1, uint32_t ctr) {
  uint32_t ks2 = k0 ^ k1 ^ 0x1BD11BDAu;
  uint32_t x0 = k0;
  uint32_t x1 = ctr + k1;
#define TFR(r) { x0 += x1; x1 = rotl32(x1, r); x1 ^= x0; }
  TFR(13) TFR(15) TFR(26) TFR(6)
  x0 += k1;  x1 += ks2 + 1u;
  TFR(17) TFR(29) TFR(16) TFR(24)
  x0 += ks2; x1 += k0 + 2u;
  TFR(13) TFR(15) TFR(26) TFR(6)
  x0 += k0;  x1 += k1 + 3u;
  TFR(17) TFR(29) TFR(16) TFR(24)
  x0 += k1;  x1 += ks2 + 4u;
  TFR(13) TFR(15) TFR(26) TFR(6)
  x0 += ks2; x1 += k0 + 5u;
#undef TFR
  return x0 ^ x1;
}

// XLA ErfInv f32 (Giles). Fast log: |u| <= 1-2^-23 so 1-u*u >= ~2^-22;
// -__logf(1-u*u) matches log1pf(-u*u) to ~1e-6 in w.
__device__ __forceinline__ float erfinv_f32(float x) {
  float t = fmaxf(1.0f - x * x, 1.0e-30f);
  float w = -__logf(t);
  float p;
  if (w < 5.0f) {
    w = w - 2.5f;
    p = 2.81022636e-08f;
    p = fmaf(p, w, 3.43273939e-07f);
    p = fmaf(p, w, -3.5233877e-06f);
    p = fmaf(p, w, -4.39150654e-06f);
    p = fmaf(p, w, 0.00021858087f);
    p = fmaf(p, w, -0.00125372503f);
    p = fmaf(p, w, -0.00417768164f);
    p = fmaf(p, w, 0.246640727f);
    p = fmaf(p, w, 1.50140941f);
  } else {
    w = sqrtf(w) - 3.0f;
    p = -0.000200214257f;
    p = fmaf(p, w, 0.000100950558f);
    p = fmaf(p, w, 0.00134934322f);
    p = fmaf(p, w, -0.00367342844f);
    p = fmaf(p, w, 0.00573950773f);
    p = fmaf(p, w, -0.0076224613f);
    p = fmaf(p, w, 0.00943887047f);
    p = fmaf(p, w, 1.00167406f);
    p = fmaf(p, w, 2.83297682f);
  }
  return p * x;
}

__device__ __forceinline__ float noise_normal(uint32_t k0, uint32_t k1, uint32_t ctr) {
  uint32_t bits = tf_mix(k0, k1, ctr);
  float f = __uint_as_float((bits >> 9) | 0x3f800000u) - 1.0f; // [0,1)
  const float lo = -0.99999994f;
  float u = fmaxf(lo, f * 2.0f + lo);
  return 1.41421356f * erfinv_f32(u);
}

// hardware packed f32->bf16 (RNE), low word = a. gfx950 has no builtin.
__device__ __forceinline__ uint32_t cvtpk(float a, float b) {
  uint32_t r;
  asm("v_cvt_pk_bf16_f32 %0, %1, %2" : "=v"(r) : "v"(a), "v"(b));
  return r;
}

// ---------------- prep: w1 -> bf16 [48,800] zero-padded; zero stats block -------
__global__ void k_prep(const float* __restrict__ w1, ushort* __restrict__ wb1,
                       float* __restrict__ st) {
  int i = blockIdx.x * 256 + threadIdx.x;
  if (i < 2048) st[i] = 0.f;     // 8-replica stats block
  if (i >= F1 * KPAD) return;
  int n = i / KPAD, k = i - n * KPAD;
  float v = (k < KDIM) ? w1[n * KDIM + k] : 0.f;
  uint32_t u = __float_as_uint(v);
  u += 0x7fffu + ((u >> 16) & 1u);
  wb1[i] = (ushort)(u >> 16);
}

// ---------------- Kernel A: MFMA bf16 GEMM1, no-LDS, + per-feature stats -------
// Block: 256 thr = 4 waves, 64 rows. Wave w: rows w*16..w*16+15 x 48 cols.
// K loop: 25 steps of 32, unrolled 2x with depth-2 register prefetch:
// while consuming step s, the loads for step s+2 are in flight (10 loads
// outstanding per lane) to cover ~900cy HBM latency at 4 waves/SIMD.
__global__ __launch_bounds__(256, 4) void k_gemm1(
    const float* __restrict__ x, const ushort* __restrict__ wb1,
    const float* __restrict__ b1, float* __restrict__ h1,
    float* __restrict__ fsum, float* __restrict__ fssq) {
  __shared__ float reds[4][48], redq[4][48];

  const int t = threadIdx.x;
  const int w = t >> 6;
  const int l = t & 63;
  const int lane16 = l & 15;
  const int quad = l >> 4;
  const int rowbase = blockIdx.x * 64;
  const int myrow = rowbase + w * 16 + lane16;   // A-operand row for this lane

  frag_cd acc[3];
#pragma unroll
  for (int ct = 0; ct < 3; ++ct)
#pragma unroll
    for (int r = 0; r < 4; ++r) acc[ct][r] = 0.f;

  // A: lane reads x[myrow][s*32 + quad*8 .. +7]
  const float* ap = x + (size_t)myrow * KDIM + quad * 8;
  // B: lane's column n = ct*16 + lane16, 8 contiguous k at quad*8
  const ushort* bp0 = wb1 + (size_t)(0 * 16 + lane16) * KPAD + quad * 8;
  const ushort* bp1 = wb1 + (size_t)(1 * 16 + lane16) * KPAD + quad * 8;
  const ushort* bp2 = wb1 + (size_t)(2 * 16 + lane16) * KPAD + quad * 8;

  // depth-2 double-buffered prefetch registers (static indexing only)
  float4 A0a, A0b, A1a, A1b;
  uint4  B0a, B0b, B0c, B1a, B1b, B1c;

  // preload steps 0 (buf0) and 1 (buf1) — always fully in range
  A0a = *(const float4*)(ap);
  A0b = *(const float4*)(ap + 4);
  B0a = *(const uint4*)(bp0);
  B0b = *(const uint4*)(bp1);
  B0c = *(const uint4*)(bp2);
  A1a = *(const float4*)(ap + 32);
  A1b = *(const float4*)(ap + 36);
  B1a = *(const uint4*)(bp0 + 32);
  B1b = *(const uint4*)(bp1 + 32);
  B1c = *(const uint4*)(bp2 + 32);

#define CONSUME(Aa, Ab, Ba, Bb, Bc)                                            \
  {                                                                            \
    UB a;                                                                      \
    a.u.x = cvtpk(Aa.x, Aa.y);                                                 \
    a.u.y = cvtpk(Aa.z, Aa.w);                                                 \
    a.u.z = cvtpk(Ab.x, Ab.y);                                                 \
    a.u.w = cvtpk(Ab.z, Ab.w);                                                 \
    UB b;                                                                      \
    b.u = Ba;                                                                  \
    acc[0] = __builtin_amdgcn_mfma_f32_16x16x32_bf16(a.f, b.f, acc[0], 0, 0, 0); \
    b.u = Bb;                                                                  \
    acc[1] = __builtin_amdgcn_mfma_f32_16x16x32_bf16(a.f, b.f, acc[1], 0, 0, 0); \
    b.u = Bc;                                                                  \
    acc[2] = __builtin_amdgcn_mfma_f32_16x16x32_bf16(a.f, b.f, acc[2], 0, 0, 0); \
  }

  // hot loop: consume steps s, s+1; prefetch steps s+2, s+3 (<= 23 -> no masks)
  for (int s = 0; s < 22; s += 2) {
    const int ko0 = (s + 2) * 32;
    const int ko1 = (s + 3) * 32;
    CONSUME(A0a, A0b, B0a, B0b, B0c)
    A0a = *(const float4*)(ap + ko0);
    A0b = *(const float4*)(ap + ko0 + 4);
    B0a = *(const uint4*)(bp0 + ko0);
    B0b = *(const uint4*)(bp1 + ko0);
    B0c = *(const uint4*)(bp2 + ko0);
    CONSUME(A1a, A1b, B1a, B1b, B1c)
    A1a = *(const float4*)(ap + ko1);
    A1b = *(const float4*)(ap + ko1 + 4);
    B1a = *(const uint4*)(bp0 + ko1);
    B1b = *(const uint4*)(bp1 + ko1);
    B1c = *(const uint4*)(bp2 + ko1);
  }
  // s=22: consume 22, prefetch 24 (A masked per-quad: 768+q*8+8<=784 -> q<2)
  {
    const int ko = 768;
    CONSUME(A0a, A0b, B0a, B0b, B0c)
    float4 z4 = make_float4(0.f, 0.f, 0.f, 0.f);
    A0a = z4; A0b = z4;
    if (quad < 2) {
      A0a = *(const float4*)(ap + ko);
      A0b = *(const float4*)(ap + ko + 4);
    }
    B0a = *(const uint4*)(bp0 + ko);   // wb1 zero-padded to 800
    B0b = *(const uint4*)(bp1 + ko);
    B0c = *(const uint4*)(bp2 + ko);
  }
  // consume 23 (no prefetch), then 24
  CONSUME(A1a, A1b, B1a, B1b, B1c)
  CONSUME(A0a, A0b, B0a, B0b, B0c)
#undef CONSUME

  // epilogue: bias, store h1, per-feature sum/ssq
  float bias[3];
#pragma unroll
  for (int ct = 0; ct < 3; ++ct) bias[ct] = b1[ct * 16 + lane16];
  float psum[3] = {0.f, 0.f, 0.f}, pssq[3] = {0.f, 0.f, 0.f};
#pragma unroll
  for (int r = 0; r < 4; ++r) {
    const int grow = rowbase + w * 16 + quad * 4 + r;   // C row = quad*4+reg
#pragma unroll
    for (int ct = 0; ct < 3; ++ct) {
      float v = acc[ct][r] + bias[ct];
      h1[(size_t)grow * F1 + ct * 16 + lane16] = v;     // C col = lane16
      psum[ct] += v;
      pssq[ct] += v * v;
    }
  }
#pragma unroll
  for (int ct = 0; ct < 3; ++ct) {
    psum[ct] += __shfl_xor(psum[ct], 16, 64);
    psum[ct] += __shfl_xor(psum[ct], 32, 64);
    pssq[ct] += __shfl_xor(pssq[ct], 16, 64);
    pssq[ct] += __shfl_xor(pssq[ct], 32, 64);
  }
  if (quad == 0) {
#pragma unroll
    for (int ct = 0; ct < 3; ++ct) {
      reds[w][ct * 16 + lane16] = psum[ct];
      redq[w][ct * 16 + lane16] = pssq[ct];
    }
  }
  __syncthreads();
  if (t < F1) {
    float s = reds[0][t] + reds[1][t] + reds[2][t] + reds[3][t];
    float q = redq[0][t] + redq[1][t] + redq[2][t] + redq[3][t];
    const int rep = blockIdx.x & 7;
    atomicAdd(&fsum[rep * 48 + t], s);
    atomicAdd(&fssq[rep * 48 + t], q);
  }
}

// ---------------- Kernel C: finalize-BN1 + noise + ReLU -> GEMM2 -> stats2 -----
// Each block redundantly (deterministically) finalizes BN params from the 8
// stat replicas.
__global__ __launch_bounds__(256) void k_layer2(
    const float* __restrict__ h1, const float* __restrict__ w2,
    const float* __restrict__ b2, const float* __restrict__ gamma1,
    const float* __restrict__ beta1, const float* __restrict__ fsum,
    const float* __restrict__ fssq, float u1,
    float* __restrict__ h2, float* __restrict__ fsum2, float* __restrict__ fssq2,
    uint32_t kna, uint32_t knb) {
  __shared__ float a1s[64][49];
  __shared__ float w2s[48][25];
  __shared__ float h2s[64][25];
  __shared__ float bnp[4][48];
  __shared__ float scal[2];

  const int t = threadIdx.x;
  const int rowbase = blockIdx.x * 64;

  // finalize BN1 stats (identical arithmetic in every block)
  float cm = 0.f, cs = 0.f;
  if (t < F1) {
    float s0 = 0.f, q0 = 0.f;
#pragma unroll
    for (int rp = 0; rp < 8; ++rp) { s0 += fsum[rp * 48 + t]; q0 += fssq[rp * 48 + t]; }
    float m = s0 * (1.f / 65536.f);
    float v = q0 * (1.f / 65536.f) - m * m;
    float r = rsqrtf(v + 1e-5f);
    float g = gamma1[t], b = beta1[t];
    bnp[0][t] = m; bnp[1][t] = r; bnp[2][t] = g; bnp[3][t] = b;
    cm = b;
    cs = g * g * r * r * v + b * b;
  }
  if (t < 64) {
#pragma unroll
    for (int off = 32; off > 0; off >>= 1) {
      cm += __shfl_down(cm, off, 64);
      cs += __shfl_down(cs, off, 64);
    }
    if (t == 0) {
      float m = cm / (float)F1;
      float SS = 65536.f * cs;
      float Ntot = 65536.f * (float)F1;
      float s2 = (SS - Ntot * m * m) / (Ntot - 1.f);  // ddof=1
      scal[0] = m;
      scal[1] = sqrtf(s2) * u1;
    }
  }
  for (int e = t; e < F2 * 48; e += 256) {
    int c = e / 48, k = e - c * 48;
    w2s[k][c] = w2[e];
  }
  __syncthreads();
  const float m1 = scal[0], su1 = scal[1];

  const int rr = t >> 2;
  const int cc0 = (t & 3) * 12;
  const int grow = rowbase + rr;
  const float* hrow = h1 + (size_t)grow * F1 + cc0;
#pragma unroll
  for (int jj = 0; jj < 12; jj += 4) {
    float4 hv = *(const float4*)(hrow + jj);
    float vv[4] = {hv.x, hv.y, hv.z, hv.w};
#pragma unroll
    for (int q = 0; q < 4; ++q) {
      int c = cc0 + jj + q;
      float bn = (vv[q] - bnp[0][c]) * bnp[1][c] * bnp[2][c] + bnp[3][c];
      uint32_t ctr = (uint32_t)grow * 48u + (uint32_t)c;
      float nz = noise_normal(kna, knb, ctr);
      float val = bn + fmaf(su1, nz, m1);
      a1s[rr][c] = fmaxf(val, 0.f);
    }
  }
  __syncthreads();

  const int rr2 = t & 63;
  const int c0 = (t >> 6) * 6;
  float acc[6] = {0.f, 0.f, 0.f, 0.f, 0.f, 0.f};
#pragma unroll
  for (int k = 0; k < 48; ++k) {
    float a = a1s[rr2][k];
#pragma unroll
    for (int j = 0; j < 6; ++j)
      acc[j] = fmaf(a, w2s[k][c0 + j], acc[j]);
  }
#pragma unroll
  for (int j = 0; j < 6; ++j)
    h2s[rr2][c0 + j] = acc[j] + b2[c0 + j];
  __syncthreads();

  for (int e = t; e < 64 * F2; e += 256) {
    int r2 = e / 24, c2 = e - r2 * 24;
    h2[(size_t)rowbase * F2 + e] = h2s[r2][c2];
  }
  if (t < F2) {
    float s = 0.f, q = 0.f;
    for (int r2 = 0; r2 < 64; ++r2) {
      float v = h2s[r2][t];
      s += v; q += v * v;
    }
    const int rep = blockIdx.x & 7;
    atomicAdd(&fsum2[rep * 24 + t], s);
    atomicAdd(&fssq2[rep * 24 + t], q);
  }
}

// ---------------- Kernel E: finalize-BN2 + noise + ReLU -> GEMM3 -> out --------
__global__ __launch_bounds__(256) void k_layer3(
    const float* __restrict__ h2, const float* __restrict__ w3,
    const float* __restrict__ b3, const float* __restrict__ gamma2,
    const float* __restrict__ beta2, const float* __restrict__ fsum2,
    const float* __restrict__ fssq2, float u2,
    float* __restrict__ out, uint32_t kna, uint32_t knb) {
  __shared__ float a2s[64][25];
  __shared__ float w3s[24][10];
  __shared__ float bnp[4][24];
  __shared__ float scal[2];

  const int t = threadIdx.x;
  const int rowbase = blockIdx.x * 64;

  float cm = 0.f, cs = 0.f;
  if (t < F2) {
    float s0 = 0.f, q0 = 0.f;
#pragma unroll
    for (int rp = 0; rp < 8; ++rp) { s0 += fsum2[rp * 24 + t]; q0 += fssq2[rp * 24 + t]; }
    float m = s0 * (1.f / 65536.f);
    float v = q0 * (1.f / 65536.f) - m * m;
    float r = rsqrtf(v + 1e-5f);
    float g = gamma2[t], b = beta2[t];
    bnp[0][t] = m; bnp[1][t] = r; bnp[2][t] = g; bnp[3][t] = b;
    cm = b;
    cs = g * g * r * r * v + b * b;
  }
  if (t < 64) {
#pragma unroll
    for (int off = 32; off > 0; off >>= 1) {
      cm += __shfl_down(cm, off, 64);
      cs += __shfl_down(cs, off, 64);
    }
    if (t == 0) {
      float m = cm / (float)F2;
      float SS = 65536.f * cs;
      float Ntot = 65536.f * (float)F2;
      float s2 = (SS - Ntot * m * m) / (Ntot - 1.f);  // ddof=1
      scal[0] = m;
      scal[1] = sqrtf(s2) * u2;
    }
  }
  if (t < F3 * F2) {
    int c = t / 24, k = t - c * 24;
    w3s[k][c] = w3[t];
  }
  __syncthreads();
  const float m2 = scal[0], su2 = scal[1];

  for (int e = t; e < 64 * F2; e += 256) {
    int r = e / 24, c = e - r * 24;
    float v = h2[(size_t)rowbase * F2 + e];
    float bn = (v - bnp[0][c]) * bnp[1][c] * bnp[2][c] + bnp[3][c];
    uint32_t ctr = (uint32_t)(rowbase * F2 + e);
    float nz = noise_normal(kna, knb, ctr);
    float val = bn + fmaf(su2, nz, m2);
    a2s[r][c] = fmaxf(val, 0.f);
  }
  __syncthreads();

  if (t < 128) {
    const int rr = t & 63;
    const int c0 = (t >> 6) * 5;
    float acc[5] = {0.f, 0.f, 0.f, 0.f, 0.f};
#pragma unroll
    for (int k = 0; k < 24; ++k) {
      float a = a2s[rr][k];
#pragma unroll
      for (int j = 0; j < 5; ++j)
        acc[j] = fmaf(a, w3s[k][c0 + j], acc[j]);
    }
    size_t ob = (size_t)(rowbase + rr) * F3 + c0;
#pragma unroll
    for (int j = 0; j < 5; ++j) out[ob + j] = acc[j] + b3[c0 + j];
  }
}

// ---------------- host threefry ----------------
static void host_tf(uint32_t k0, uint32_t k1, uint32_t c0, uint32_t c1,
                    uint32_t& o0, uint32_t& o1) {
  uint32_t ks2 = k0 ^ k1 ^ 0x1BD11BDAu;
  uint32_t x0 = c0 + k0, x1 = c1 + k1;
  auto R = [&](int r) { x0 += x1; x1 = (x1 << r) | (x1 >> (32 - r)); x1 ^= x0; };
  R(13); R(15); R(26); R(6);  x0 += k1;  x1 += ks2 + 1u;
  R(17); R(29); R(16); R(24); x0 += ks2; x1 += k0 + 2u;
  R(13); R(15); R(26); R(6);  x0 += k0;  x1 += k1 + 3u;
  R(17); R(29); R(16); R(24); x0 += k1;  x1 += ks2 + 4u;
  R(13); R(15); R(26); R(6);  x0 += ks2; x1 += k0 + 5u;
  o0 = x0; o1 = x1;
}

static float host_uniform12(uint32_t seed) {
  uint32_t ka, kb, t0, t1;
  host_tf(0u, seed, 0u, 0u, ka, kb);     // foldlike split, ctr 0 -> ku
  host_tf(ka, kb, 0u, 0u, t0, t1);       // random_bits of shape ()
  uint32_t bits = t0 ^ t1;               // partitionable: XOR of both words
  uint32_t fb = (bits >> 9) | 0x3f800000u;
  float f;
  std::memcpy(&f, &fb, 4);
  return f;
}

extern "C" void kernel_launch(void* const* d_in, const int* in_sizes, int n_in,
                              void* d_out, int out_size, void* d_ws, size_t ws_size,
                              hipStream_t stream) {
  (void)in_sizes; (void)n_in; (void)out_size; (void)ws_size;
  const float* x      = (const float*)d_in[0];
  const float* w1     = (const float*)d_in[1];
  const float* b1     = (const float*)d_in[2];
  const float* gamma1 = (const float*)d_in[3];
  const float* beta1  = (const float*)d_in[4];
  const float* w2     = (const float*)d_in[5];
  const float* b2     = (const float*)d_in[6];
  const float* gamma2 = (const float*)d_in[7];
  const float* beta2  = (const float*)d_in[8];
  const float* w3     = (const float*)d_in[9];
  const float* b3     = (const float*)d_in[10];
  float* out = (float*)d_out;

  float* h1 = (float*)d_ws;                       // 65536*48
  float* h2 = h1 + (size_t)MROWS * F1;            // 65536*24
  float* st = h2 + (size_t)MROWS * F2;            // stats block (2048 floats)
  ushort* wb1 = (ushort*)(st + 2048);             // 48*800 bf16

  uint32_t kn1a, kn1b, kn2a, kn2b;
  host_tf(0u, 1234u, 0u, 1u, kn1a, kn1b);         // kn of foldlike split(key(1234))
  host_tf(0u, 5678u, 0u, 1u, kn2a, kn2b);         // kn of foldlike split(key(5678))
  float u1 = host_uniform12(1234u);
  float u2 = host_uniform12(5678u);

  // st layout (8 replicas each): fsum1[8][48]@0  fssq1[8][48]@384
  //                              fsum2[8][24]@768 fssq2[8][24]@960
  k_prep<<<(F1 * KPAD + 255) / 256, 256, 0, stream>>>(w1, wb1, st);
  k_gemm1<<<MROWS / 64, 256, 0, stream>>>(x, wb1, b1, h1, st + 0, st + 384);
  k_layer2<<<MROWS / 64, 256, 0, stream>>>(h1, w2, b2, gamma1, beta1,
                                           st + 0, st + 384, u1,
                                           h2, st + 768, st + 960, kn1a, kn1b);
  k_layer3<<<MROWS / 64, 256, 0, stream>>>(h2, w3, b3, gamma2, beta2,
                                           st + 768, st + 960, u2,
                                           out, kn2a, kn2b);
}